// Round 14
// baseline (202.993 us; speedup 1.0000x reference)
//
#include <hip/hip_runtime.h>
#include <hip/hip_bf16.h>
#include <math.h>

#define NN 20000
#define NE 320000
#define C0I 32
#define C1I 16
#define C0O 64
#define C1O 16
#define EPSF 1e-8f
#define STAGE_TOTAL 1671264   // total staged f32 elements
#define STAGE_V4    417816    // /4
#define RSTR 84               // LDS row stride (84 mod 32 = 20 -> 2-way max, free)
#define FGS  193              // FG row: aggA(48) | C(96, d*32+c) | x1agg(48, c*3+d) | z

using bf16 = __hip_bfloat16;

__device__ __forceinline__ float bb2f(unsigned short u) {
    return __uint_as_float(((unsigned)u) << 16);
}

// wave-level LDS fence: drain outstanding ds ops + forbid compile-time motion
__device__ __forceinline__ void lds_fence() {
    asm volatile("s_waitcnt lgkmcnt(0)" ::: "memory");
    __builtin_amdgcn_sched_barrier(0);
}

// ---- kA: detect dtype + stage all float inputs as f32 + dst histogram ----
__global__ __launch_bounds__(256) void se3_convert(
    const void* s0, const void* s1, const void* s2, const void* s3,
    const void* s4, const void* s5, const void* s6, const void* s7,
    const void* s8, const void* s9, const void* s10, const void* s11,
    const int* __restrict__ ei,
    int* __restrict__ flag, float* __restrict__ dst, int* __restrict__ cnt) {
    __shared__ int sj;
    if (threadIdx.x == 0) sj = 0;
    __syncthreads();
    {   // f32 data read as bf16 at even indices shows junk exponents
        const unsigned short* p = (const unsigned short*)s0;
        bool junk = false;
        int i0 = threadIdx.x * 8;
#pragma unroll
        for (int k = 0; k < 4; ++k) {
            float v = bb2f(p[i0 + k * 2]);
            if (!(fabsf(v) < 1e3f)) junk = true;
        }
        if (junk) atomicOr(&sj, 1);
    }
    __syncthreads();
    int isf32 = sj;
    int gid = blockIdx.x * 256 + threadIdx.x;
    if (gid == 0) *flag = isf32;
    if (gid < NE) atomicAdd(&cnt[ei[NE + gid]], 1);   // histogram (cnt pre-zeroed)
    if (gid >= STAGE_V4) return;

    const void* src; int off;  // vec4 units
    if      (gid < 160000) { src = s0;  off = gid; }
    else if (gid < 400000) { src = s1;  off = gid - 160000; }
    else if (gid < 415000) { src = s2;  off = gid - 400000; }
    else if (gid < 415512) { src = s3;  off = gid - 415000; }
    else if (gid < 416024) { src = s4;  off = gid - 415512; }
    else if (gid < 416280) { src = s5;  off = gid - 416024; }
    else if (gid < 416792) { src = s6;  off = gid - 416280; }
    else if (gid < 417048) { src = s7;  off = gid - 416792; }
    else if (gid < 417176) { src = s8;  off = gid - 417048; }
    else if (gid < 417240) { src = s9;  off = gid - 417176; }
    else if (gid < 417752) { src = s10; off = gid - 417240; }
    else                   { src = s11; off = gid - 417752; }

    float4 v;
    if (isf32) {
        v = ((const float4*)src)[off];
    } else {
        ushort4 u = ((const ushort4*)src)[off];
        v = make_float4(bb2f(u.x), bb2f(u.y), bb2f(u.z), bb2f(u.w));
    }
    ((float4*)dst)[gid] = v;
}

// ---- kB: block 0: exclusive scan cnt -> rowptr,wptr; blocks 1-8: weight combines ----
__global__ __launch_bounds__(1024) void se3_scanw(
    const int* __restrict__ cnt, int* __restrict__ rowptr, int* __restrict__ wptr,
    const float* __restrict__ wq0, const float* __restrict__ wk00,
    const float* __restrict__ wk10,
    const float* __restrict__ wv00, const float* __restrict__ wv10,
    const float* __restrict__ wv01, const float* __restrict__ wv11,
    const float* __restrict__ ws0, const float* __restrict__ ws1,
    float* __restrict__ wqkc, float* __restrict__ M0cat, float* __restrict__ M1cat) {
    if (blockIdx.x == 0) {
        __shared__ int tmp[1024];
        int t = threadIdx.x;
        int base = t * 20;
        int v[20]; int s = 0;
#pragma unroll
        for (int i = 0; i < 20; ++i) {
            int idx = base + i;
            int c = (idx < NN) ? cnt[idx] : 0;
            v[i] = s; s += c;
        }
        tmp[t] = s;
        __syncthreads();
        for (int off = 1; off < 1024; off <<= 1) {
            int x = (t >= off) ? tmp[t - off] : 0;
            __syncthreads();
            tmp[t] += x;
            __syncthreads();
        }
        int tb = (t > 0) ? tmp[t - 1] : 0;
#pragma unroll
        for (int i = 0; i < 20; ++i) {
            int idx = base + i;
            if (idx < NN) { int r = tb + v[i]; rowptr[idx] = r; wptr[idx] = r; }
        }
        if (t == 1023) rowptr[NN] = NE;
    } else {
        int i = (blockIdx.x - 1) * 1024 + threadIdx.x;
        if (i < 1536) {
            int cp = i / 48, c = i % 48;
            float a = 0.f;
            if (c < 32) { for (int j = 0; j < C0O; ++j) a += wq0[cp*C0O+j] * wk00[c*C0O+j]; }
            else        { for (int j = 0; j < C0O; ++j) a += wq0[cp*C0O+j] * wk10[(c-32)*C0O+j]; }
            wqkc[i] = a;
        } else if (i < 1536 + 5120) {
            int k = i - 1536;
            int r = k >> 6, j = k & 63;
            M0cat[k] = (r < 32) ? wv00[r*64+j] : (r < 48) ? wv10[(r-32)*64+j] : ws0[(r-48)*64+j];
        } else if (i < 1536 + 5120 + 1024) {
            int k = i - 6656;
            int r = k >> 4, f = k & 15;
            M1cat[k] = (r < 16) ? wv11[r*16+f] : (r < 48) ? wv01[(r-16)*16+f] : ws1[(r-48)*16+f];
        }
    }
}

// ---- kC: blocks [0,1250): CSR scatter (src AND dst); blocks [1250,6250): qvec ----
__global__ __launch_bounds__(256) void se3_scatqv(
    const int* __restrict__ ei, int* __restrict__ wptr,
    int* __restrict__ csr_src, int* __restrict__ csr_dst,
    const float* __restrict__ x0, const float* __restrict__ wqkc,
    float* __restrict__ qvec) {
    int b = blockIdx.x;
    if (b < 1250) {
        int e = b * 256 + threadIdx.x;
        if (e < NE) {
            int d = ei[NE + e];
            int off = atomicAdd(&wptr[d], 1);
            csr_src[off] = ei[e];
            csr_dst[off] = d;
        }
    } else {
        __shared__ float sw[1536];
        for (int i = threadIdx.x; i < 1536; i += 256) sw[i] = wqkc[i];
        __syncthreads();
        int wv = threadIdx.x >> 6, lane = threadIdx.x & 63;
        int n = (b - 1250) * 4 + wv;
        float x0v = (lane < 32) ? x0[(size_t)n * 32 + lane] : 0.f;
        int li = (lane < 48) ? lane : 0;
        float qh = 0.f;
        for (int cp = 0; cp < 32; ++cp)
            qh += __shfl(x0v, cp) * sw[cp * 48 + li];
        if (lane < 48) qvec[(size_t)n * 48 + lane] = qh;
    }
}

// ---- kF: UNIFORM edge-window waves. Wave w handles CSR window [16w,16w+16).
//      No per-node loop; commutative softmax (exp without max-sub, safe for
//      |logit| up to ~80; clamped); segment-flush via atomicAdd into FG.
//      20000 identical waves -> zero imbalance, single latency exposure. ----
__global__ __launch_bounds__(256) void se3_fused(
    const float* __restrict__ x0, const float* __restrict__ x1,
    const float* __restrict__ pos, const float* __restrict__ qvec,
    const int* __restrict__ csr_src, const int* __restrict__ csr_dst,
    float* __restrict__ FG) {
    __shared__ __align__(16) float rows[4][16][RSTR];
    __shared__ __align__(16) float sW4[4][16][4];
    __shared__ int sdst[4][16];

    int tid = threadIdx.x, wv = tid >> 6, lane = tid & 63;
    float (*R)[RSTR] = rows[wv];
    float (*W4)[4] = sW4[wv];
    int* dstS = sdst[wv];
    int p0 = (blockIdx.x * 4 + wv) * 16;     // grid 5000 -> windows cover NE exactly
    int e4 = lane >> 2, j4 = lane & 3;
    int cc = (lane >= 32 && lane < 48) ? (lane - 32) : 0;

    // ---- stage: 4 lanes per edge (all 64 lanes active; e4<16 always) ----
    int s_e = csr_src[p0 + e4];
    int d_e = csr_dst[p0 + e4];
    float rx = pos[d_e*3]   - pos[s_e*3];
    float ry = pos[d_e*3+1] - pos[s_e*3+1];
    float rz = pos[d_e*3+2] - pos[s_e*3+2];
    float inv = 1.f / (sqrtf(rx*rx + ry*ry + rz*rz) + EPSF);
    float Yx = rx*inv, Yy = ry*inv, Yz = rz*inv;
    {
        const float4* px0 = (const float4*)(x0 + (size_t)s_e * 32);
        *(float4*)&R[e4][j4*8]   = px0[j4*2];
        *(float4*)&R[e4][j4*8+4] = px0[j4*2+1];
        const float4* px1 = (const float4*)(x1 + (size_t)s_e * 48);
        *(float4*)&R[e4][32+j4*12]   = px1[j4*3];
        *(float4*)&R[e4][32+j4*12+4] = px1[j4*3+1];
        *(float4*)&R[e4][32+j4*12+8] = px1[j4*3+2];
        if (j4 == 0) dstS[e4] = d_e;
    }
    lds_fence();   // stage writes visible before cross-lane reads

    // ---- logits: lane (e4,j4) covers c = j4+4k; q gathered from qvec[d_e] ----
    float part = 0.f;
    {
        const float* qrow = qvec + (size_t)d_e * 48;
#pragma unroll
        for (int k = 0; k < 12; ++k) {
            int c = j4 + 4*k;
            float kv;
            if (c < 32) kv = R[e4][c];
            else {
                int c1 = c - 32;
                kv = R[e4][32+3*c1]*Yx + R[e4][32+3*c1+1]*Yy + R[e4][32+3*c1+2]*Yz;
            }
            part += kv * qrow[c];
        }
    }
    part += __shfl_xor(part, 1);
    part += __shfl_xor(part, 2);
    float lg = part * 0.125f;                     // 1/sqrt(64)
    float w = __expf(fminf(lg, 80.f));            // commutative softmax weight
    if (j4 == 0) *(float4*)&W4[e4][0] = make_float4(w, Yx, Yy, Yz);
    lds_fence();   // W4 writes visible before Phase-B reads

    // ---- Phase B: lane = feature; accumulate over window, flush per segment ----
    float aA = 0.f, aB = 0.f, Cx = 0.f, Cy = 0.f, Cz = 0.f, zacc = 0.f;
#pragma unroll 4
    for (int e = 0; e < 16; ++e) {
        float4 wy = *(const float4*)&W4[e][0];
        float we = wy.x, Y0 = wy.y, Y1 = wy.z, Y2 = wy.w;
        float x1v = (lane < 48) ? R[e][32 + lane] : 0.f;
        if (lane < 32) {
            float wx = we * R[e][lane];
            aA += wx; Cx += wx * Y0; Cy += wx * Y1; Cz += wx * Y2;
        } else if (lane < 48) {
            float xd = R[e][32+3*cc]*Y0 + R[e][32+3*cc+1]*Y1 + R[e][32+3*cc+2]*Y2;
            aA += we * xd;
        }
        aB += we * x1v;
        zacc += we;
        int de = dstS[e];
        int dn = (e < 15) ? dstS[e + 1] : -1;
        if (dn != de) {   // wave-uniform flush (CSR is dst-sorted -> runs)
            float* fg = FG + (size_t)de * FGS;
            if (lane < 48) {
                atomicAdd(&fg[lane], aA);
                atomicAdd(&fg[144 + lane], aB);
            }
            if (lane < 32) {
                atomicAdd(&fg[48 + lane], Cx);
                atomicAdd(&fg[80 + lane], Cy);
                atomicAdd(&fg[112 + lane], Cz);
            }
            if (lane == 48) atomicAdd(&fg[192], zacc);
            aA = 0.f; aB = 0.f; Cx = 0.f; Cy = 0.f; Cz = 0.f; zacc = 0.f;
        }
    }
}

// ---- kG: epilogue tiled GEMM, 32 nodes/block, block-synced LDS. ----
__global__ __launch_bounds__(256) void se3_epi(
    const float* __restrict__ FG, const float* __restrict__ x0,
    const float* __restrict__ x1,
    const float* __restrict__ M0cat, const float* __restrict__ M1cat,
    const int* __restrict__ flag, void* __restrict__ out) {
    __shared__ float sM0[80][64];
    __shared__ float sM1[64][16];
    __shared__ float sF[32][80];
    __shared__ float sG[32][194];
    int tid = threadIdx.x;
    int n0 = blockIdx.x * 32;
    for (int i = tid; i < 5120; i += 256) sM0[i >> 6][i & 63] = M0cat[i];
    for (int i = tid; i < 1024; i += 256) sM1[i >> 4][i & 15] = M1cat[i];
    for (int i = tid; i < 2560; i += 256) {
        int ii = i / 80, c = i - ii * 80;
        int n = n0 + ii;
        float iz = 1.f / (FG[(size_t)n * FGS + 192] + EPSF);
        sF[ii][c] = (c < 48) ? FG[(size_t)n * FGS + c] * iz
                             : x0[(size_t)n * 32 + (c - 48)];
    }
    for (int i = tid; i < 6144; i += 256) {
        int ii = i / 192, t = i - ii * 192;
        int r = t / 3, d = t - 3 * r;
        int n = n0 + ii;
        float iz = 1.f / (FG[(size_t)n * FGS + 192] + EPSF);
        float v;
        if (r < 16)      v = FG[(size_t)n * FGS + 144 + t] * iz;            // x1agg (c*3+d)
        else if (r < 48) v = FG[(size_t)n * FGS + 48 + d*32 + (r-16)] * iz; // C[d][c]
        else             v = x1[(size_t)n * 48 + 3*(r-48) + d];             // x1n
        sG[ii][t] = v;
    }
    __syncthreads();
    int isf32 = *flag;
    // out0
    {
        int j = tid & 63, ng = tid >> 6;
        float acc[8];
#pragma unroll
        for (int k = 0; k < 8; ++k) acc[k] = 0.f;
        for (int r = 0; r < 80; ++r) {
            float mv = sM0[r][j];
#pragma unroll
            for (int k = 0; k < 8; ++k) acc[k] += sF[ng*8 + k][r] * mv;
        }
#pragma unroll
        for (int k = 0; k < 8; ++k) {
            size_t o = (size_t)(n0 + ng*8 + k) * 64 + j;
            if (isf32) ((float*)out)[o] = acc[k];
            else       ((bf16*)out)[o] = __float2bfloat16(acc[k]);
        }
    }
    // out1
    {
        int f = tid & 15, ig = tid >> 4;
        float a0x=0.f,a0y=0.f,a0z=0.f,a1x=0.f,a1y=0.f,a1z=0.f;
        for (int r = 0; r < 64; ++r) {
            float mv = sM1[r][f];
            a0x += sG[ig][3*r+0] * mv;
            a0y += sG[ig][3*r+1] * mv;
            a0z += sG[ig][3*r+2] * mv;
            a1x += sG[ig+16][3*r+0] * mv;
            a1y += sG[ig+16][3*r+1] * mv;
            a1z += sG[ig+16][3*r+2] * mv;
        }
        size_t b0 = (size_t)NN*64 + (size_t)(n0+ig)*48 + f*3;
        size_t b1 = (size_t)NN*64 + (size_t)(n0+ig+16)*48 + f*3;
        if (isf32) {
            ((float*)out)[b0] = a0x; ((float*)out)[b0+1] = a0y; ((float*)out)[b0+2] = a0z;
            ((float*)out)[b1] = a1x; ((float*)out)[b1+1] = a1y; ((float*)out)[b1+2] = a1z;
        } else {
            ((bf16*)out)[b0] = __float2bfloat16(a0x);
            ((bf16*)out)[b0+1] = __float2bfloat16(a0y);
            ((bf16*)out)[b0+2] = __float2bfloat16(a0z);
            ((bf16*)out)[b1] = __float2bfloat16(a1x);
            ((bf16*)out)[b1+1] = __float2bfloat16(a1y);
            ((bf16*)out)[b1+2] = __float2bfloat16(a1z);
        }
    }
}

extern "C" void kernel_launch(void* const* d_in, const int* in_sizes, int n_in,
                              void* d_out, int out_size, void* d_ws, size_t ws_size,
                              hipStream_t stream) {
    const int* ei = (const int*)d_in[3];

    int* flag  = (int*)d_ws;
    float* ws  = (float*)d_ws + 16;
    float* x0f  = ws;                 // 640000
    float* x1f  = x0f + 640000;       // 960000
    float* posf = x1f + 960000;       // 60000
    float* wq0    = posf + 60000;     // 2048
    float* wk00   = wq0 + 2048;       // 2048
    float* wk10   = wk00 + 2048;      // 1024
    float* wv00   = wk10 + 1024;      // 2048
    float* wv10   = wv00 + 2048;      // 1024
    float* wv01   = wv10 + 1024;      // 512
    float* wv11   = wv01 + 512;       // 256
    float* wself0 = wv11 + 256;       // 2048
    float* wself1 = wself0 + 2048;    // 256
    float* wqkc  = ws + STAGE_TOTAL;          // 1536
    float* M0cat = wqkc + 1536;               // 5120
    float* M1cat = M0cat + 5120;              // 1024
    int* cnt     = (int*)(M1cat + 1024);      // NN
    int* rowptr  = cnt + NN;                  // NN+1
    int* wptr    = rowptr + NN + 1;           // NN
    int* csr_src = wptr + NN;                 // NE
    int* csr_dst = csr_src + NE;              // NE
    float* qvec  = (float*)(csr_dst + NE);    // NN*48
    float* FG    = qvec + (size_t)NN * 48;    // NN*193  (total ~28.8 MB)

    hipMemsetAsync(cnt, 0, NN * sizeof(int), stream);
    hipMemsetAsync(FG, 0, (size_t)NN * FGS * sizeof(float), stream);
    se3_convert<<<1633, 256, 0, stream>>>(d_in[0], d_in[1], d_in[2],
        d_in[4], d_in[5], d_in[6], d_in[7], d_in[8], d_in[9], d_in[10], d_in[11], d_in[12],
        ei, flag, ws, cnt);
    se3_scanw<<<9, 1024, 0, stream>>>(cnt, rowptr, wptr,
        wq0, wk00, wk10, wv00, wv10, wv01, wv11, wself0, wself1,
        wqkc, M0cat, M1cat);
    se3_scatqv<<<6250, 256, 0, stream>>>(ei, wptr, csr_src, csr_dst, x0f, wqkc, qvec);
    se3_fused<<<5000, 256, 0, stream>>>(x0f, x1f, posf, qvec, csr_src, csr_dst, FG);
    se3_epi<<<625, 256, 0, stream>>>(FG, x0f, x1f, M0cat, M1cat, flag, d_out);
}